// Round 8
// baseline (183.239 us; speedup 1.0000x reference)
//
#include <hip/hip_runtime.h>
#include <hip/hip_bf16.h>
#include <string.h>

typedef __hip_bfloat16 bf16;
typedef __attribute__((ext_vector_type(8))) short short8;
typedef __attribute__((ext_vector_type(4))) short short4v;
typedef __attribute__((ext_vector_type(4))) float f32x4;

__device__ __forceinline__ float s2f(short s) {
    return __uint_as_float(((unsigned)(unsigned short)s) << 16);
}
__device__ __forceinline__ short f2s(float v) {
    bf16 t = __float2bfloat16(v); short s; __builtin_memcpy(&s, &t, 2); return s;
}

#define HWD 16384    // 128*128

// ---------------------------------------------------------------------------
// K01: transpose x (b,256,4096) fp32 -> xpm (b,4096,256) bf16 via swizzled
// LDS tile, then MFMA the off/ast GEMM straight from LDS.
// grid 512 = 4 b * 128 tiles(32 px); 512 threads (8 waves: 2 mh x 4 wq).
// ---------------------------------------------------------------------------
__global__ __launch_bounds__(512) void k01_xpose_off(const float* __restrict__ x,
        const float* __restrict__ w_off, const float* __restrict__ b_off,
        const float* __restrict__ w_ast, const float* __restrict__ b_ast,
        bf16* __restrict__ xpm, float* __restrict__ offpm)
{
    __shared__ __align__(16) short tileS[32 * 256];   // 16 KB, swizzled
    const int b = blockIdx.x >> 7;
    const int p0 = (blockIdx.x & 127) << 5;
    const int lane = threadIdx.x & 63;
    const int wave = threadIdx.x >> 6;      // 0..7
    const int n = lane & 15, quad = lane >> 4;
    const int wq = wave & 3;                // N-group
    const int mh = wave >> 2;               // m-half (16 rows each)

    const int j = (wq << 4) + n, oc = j >> 1, kind = j & 1;
    short8 bfrag[8];
    const float* wrow = (kind ? w_ast : w_off) + oc * 256 + quad * 8;
#pragma unroll
    for (int kc = 0; kc < 8; ++kc) {
        float4 lo = *(const float4*)(wrow + kc * 32);
        float4 hi = *(const float4*)(wrow + kc * 32 + 4);
        short8 f;
        f[0] = f2s(lo.x); f[1] = f2s(lo.y); f[2] = f2s(lo.z); f[3] = f2s(lo.w);
        f[4] = f2s(hi.x); f[5] = f2s(hi.y); f[6] = f2s(hi.z); f[7] = f2s(hi.w);
        bfrag[kc] = f;
    }
    float bias = kind ? b_ast[oc] : b_off[oc];

    // --- phase 1: fill swizzled LDS tile (32 px x 256 ch) ---
    {
        const float* xb = x + ((size_t)b << 20);
        const int px = threadIdx.x & 31;
        const int gi0 = threadIdx.x >> 5;     // 0..15
#pragma unroll
        for (int it = 0; it < 2; ++it) {
            int gi = gi0 + (it << 4);         // 8-ch group 0..31
            int cbase = gi << 3;
            short8 pk;
#pragma unroll
            for (int jj = 0; jj < 8; ++jj)
                pk[jj] = f2s(xb[((size_t)(cbase + jj) << 12) + p0 + px]);
            int slot = gi ^ (px & 7);
            *(short8*)&tileS[(px << 8) + (slot << 3)] = pk;
        }
    }
    __syncthreads();

    // --- phase 2: coalesced xpm store from LDS (4 rows per wave) ---
    {
        short* ob = (short*)xpm + ((size_t)((b << 12) + p0) << 8);
#pragma unroll
        for (int rr = 0; rr < 4; ++rr) {
            int r = (wave << 2) + rr;
            short4v v = *(const short4v*)&tileS[(r << 8)
                        + ((((lane >> 1) ^ (r & 7)) << 3) | ((lane & 1) << 2))];
            *(short4v*)(ob + ((size_t)r << 8) + (lane << 2)) = v;
        }
    }

    // --- phase 3: MFMA GEMM from LDS, gated epilogue -> offpm ---
    float* obase = offpm + ((size_t)(b << 12) << 5);
    f32x4 acc = {0.f, 0.f, 0.f, 0.f};
#pragma unroll
    for (int kc = 0; kc < 8; ++kc) {
        int slot = (((kc << 2) + quad) ^ (n & 7)) << 3;
        short8 a = *(const short8*)&tileS[((mh * 16 + n) << 8) + slot];
        acc = __builtin_amdgcn_mfma_f32_16x16x32_bf16(a, bfrag[kc], acc, 0, 0, 0);
    }
#pragma unroll
    for (int r = 0; r < 4; ++r) {
        float v0 = acc[r] + bias;
        float p0v = __shfl_xor(v0, 1, 64);
        if (!(n & 1)) {
            int px = p0 + mh * 16 + quad * 4 + r;
            obase[((size_t)px << 5) + oc] = v0 * (1.f / (1.f + expf(-p0v)));
        }
    }
}

// ---------------------------------------------------------------------------
// K234: def_sample + comp MFMA + kern/toff epilogue + 3x3 filter.
// R8 = R5 geometry + R6 swizzle + R7 pipeline:
//   4x8 interior tile, 6x10=60-row halo, LDS ~46.8KB -> 3 blocks/CU
//   (24 waves/CU, 75% cap); XCD-chunked swizzle keeps per-XCD tap
//   footprint ~1.4MB (L2-resident) -- R5 failed without it (FETCH 84MB);
//   2-deep pipelined gather (depth 2 to fit VGPR<=85 at (512,6)).
// grid 2048 = 4 b * 512 tiles; 512 threads.
// ---------------------------------------------------------------------------
__global__ __launch_bounds__(512, 6) void k234_defsample_comp_filter(
        const bf16* __restrict__ xpm, const float* __restrict__ offpm,
        const float* __restrict__ cw, const float* __restrict__ cb,
        const float* __restrict__ fw_g, const float* __restrict__ fb,
        const float* __restrict__ tw, const float* __restrict__ tb,
        const float* __restrict__ taw, const float* __restrict__ tab,
        bf16* __restrict__ xfilt, float* __restrict__ toff)
{
    __shared__ __align__(16) short xupS[60 * 256];    // 30 KB, swizzled rows
    __shared__ __align__(16) float smc[32][65];       // 8.3 KB
    __shared__ __align__(16) float fwS[64 * 12];      // 3 KB
    __shared__ __align__(16) float swS[64 * 16];      // 4 KB
    __shared__ __align__(16) short kernS[32][24];     // 1.5 KB

    for (int i = threadIdx.x; i < 64 * 12; i += 512) {
        int c = i / 12, k = i % 12;
        fwS[i] = (k < 9) ? fw_g[k * 64 + c] : 0.f;
    }
    for (int i = threadIdx.x; i < 64 * 16; i += 512) {
        int c = i >> 4, jj = i & 15;
        int oc = jj >> 1, kind = jj & 1;
        swS[i] = kind ? taw[oc * 64 + c] : tw[oc * 64 + c];
    }

    // XCD-chunked bijective swizzle (grid 2048): XCD r owns contiguous
    // vbid [r*256, (r+1)*256) = a 64-px-row band of one batch image.
    const int nb = gridDim.x >> 3;
    const int vbid = (blockIdx.x & 7) * nb + (blockIdx.x >> 3);
    const int b = vbid >> 9;
    const int tile = vbid & 511;
    const int ty = tile >> 4, tx = tile & 15;    // 4-row x 8-col tiles
    const int lane = threadIdx.x & 63;
    const int wave = threadIdx.x >> 6;       // 0..7
    const int n = lane & 15, quad = lane >> 4;
    const int wq = wave & 3, mh = wave >> 2;
    const int ocb = wq << 4;

    // --- phase 1: gather 60 halo rows; 2-deep pipelined tap loads ---
    {
        const short* xsrc = (const short*)xpm + ((size_t)b << 20);
        const int ph = lane >> 5;             // px half
        const int cl = lane & 31;             // 8-ch chunk
        const int e = cl << 3;                // shorts
        const int g = cl >> 3;                // offset group
        const int base = (wave << 1) + ph;    // 0..15

        float2 fo[4];
#pragma unroll
        for (int it = 0; it < 4; ++it) {
            int l = base + (it << 4);
            if (l < 60) {
                int lhy = (l * 205) >> 11;    // l / 10
                int lwx = l - lhy * 10;
                int hy = min(max(ty * 4 - 1 + lhy, 0), 127);
                int wx = min(max(tx * 8 - 1 + lwx, 0), 127);
                int och = (g << 3) + ((hy & 1) << 2) + ((wx & 1) << 1);
                fo[it] = *(const float2*)(offpm
                        + ((size_t)((b << 12) + ((hy >> 1) << 6) + (wx >> 1)) << 5)
                        + och);
            }
        }

        short8 t00[2], t01[2], t10[2], t11[2];

#define K234_ISSUE(it, slot) { \
            int l = base + ((it) << 4); \
            if (l < 60) { \
                int lhy = (l * 205) >> 11; \
                int lwx = l - lhy * 10; \
                int hy = min(max(ty * 4 - 1 + lhy, 0), 127); \
                int wx = min(max(tx * 8 - 1 + lwx, 0), 127); \
                float ix = (wx + 0.5f + fo[it].x) * 0.5f - 0.5f; \
                float iy = (hy + 0.5f + fo[it].y) * 0.5f - 0.5f; \
                ix = fminf(fmaxf(ix, 0.f), 63.f); \
                iy = fminf(fmaxf(iy, 0.f), 63.f); \
                int x0 = (int)ix, y0 = (int)iy; \
                int x1 = min(x0 + 1, 63), y1 = min(y0 + 1, 63); \
                t00[slot] = *(const short8*)(xsrc + (((size_t)(y0 << 6) + x0) << 8) + e); \
                t01[slot] = *(const short8*)(xsrc + (((size_t)(y0 << 6) + x1) << 8) + e); \
                t10[slot] = *(const short8*)(xsrc + (((size_t)(y1 << 6) + x0) << 8) + e); \
                t11[slot] = *(const short8*)(xsrc + (((size_t)(y1 << 6) + x1) << 8) + e); \
            } }

#define K234_CONSUME(it, slot) { \
            int l = base + ((it) << 4); \
            if (l < 60) { \
                int lhy = (l * 205) >> 11; \
                int lwx = l - lhy * 10; \
                int hy = min(max(ty * 4 - 1 + lhy, 0), 127); \
                int wx = min(max(tx * 8 - 1 + lwx, 0), 127); \
                float ix = (wx + 0.5f + fo[it].x) * 0.5f - 0.5f; \
                float iy = (hy + 0.5f + fo[it].y) * 0.5f - 0.5f; \
                ix = fminf(fmaxf(ix, 0.f), 63.f); \
                iy = fminf(fmaxf(iy, 0.f), 63.f); \
                float fx = ix - floorf(ix), fy = iy - floorf(iy); \
                float w00 = (1.f - fx) * (1.f - fy), w01 = fx * (1.f - fy); \
                float w10 = (1.f - fx) * fy,        w11 = fx * fy; \
                short8 pk; \
                _Pragma("unroll") \
                for (int jj = 0; jj < 8; ++jj) { \
                    float v = w00 * s2f(t00[slot][jj]) + w01 * s2f(t01[slot][jj]) \
                            + w10 * s2f(t10[slot][jj]) + w11 * s2f(t11[slot][jj]); \
                    pk[jj] = f2s(v); \
                } \
                int sl2 = cl ^ (l & 7); \
                *(short8*)&xupS[(l << 8) + (sl2 << 3)] = pk; \
            } }

        K234_ISSUE(0, 0)
        K234_ISSUE(1, 1)
        K234_CONSUME(0, 0)  K234_ISSUE(2, 0)
        K234_CONSUME(1, 1)  K234_ISSUE(3, 1)
        K234_CONSUME(2, 0)
        K234_CONSUME(3, 1)
#undef K234_ISSUE
#undef K234_CONSUME
    }

    // --- B fragments for comp GEMM (loaded after gather: VGPR headroom) ---
    short8 bfrag[8];
    {
        const float* wrow = cw + (ocb + n) * 256 + quad * 8;
#pragma unroll
        for (int kc = 0; kc < 8; ++kc) {
            float4 lo = *(const float4*)(wrow + kc * 32);
            float4 hi = *(const float4*)(wrow + kc * 32 + 4);
            short8 f;
            f[0] = f2s(lo.x); f[1] = f2s(lo.y); f[2] = f2s(lo.z); f[3] = f2s(lo.w);
            f[4] = f2s(hi.x); f[5] = f2s(hi.y); f[6] = f2s(hi.z); f[7] = f2s(hi.w);
            bfrag[kc] = f;
        }
    }
    float bias = cb[ocb + n];
    __syncthreads();

    // --- phase 2: comp MFMA; wave (mh,wq): 16 rows at mh*16, cols wq*16 ---
    const int m0 = mh << 4;
    const int pA = m0 + n;
    const int rA = ((pA >> 3) + 1) * 10 + (pA & 7) + 1;
    f32x4 acc = {0.f,0.f,0.f,0.f};
#pragma unroll
    for (int kc = 0; kc < 8; ++kc) {
        int sp = (kc << 2) + quad;
        short8 a = *(const short8*)&xupS[(rA << 8) + ((sp ^ (rA & 7)) << 3)];
        acc = __builtin_amdgcn_mfma_f32_16x16x32_bf16(a, bfrag[kc], acc, 0, 0, 0);
    }
#pragma unroll
    for (int r = 0; r < 4; ++r)
        smc[m0 + quad * 4 + r][ocb + n] = acc[r] + bias;
    __syncthreads();

    // --- phase 3: kern softmax (wave 0, lanes<32) / toff (waves 1..4) ---
    const int q = wave;
    if (q == 0) {
        if (lane < 32) {
            const int px = lane;
            float a[9];
#pragma unroll
            for (int k = 0; k < 9; ++k) a[k] = fb[k];
            for (int c = 0; c < 64; ++c) {
                float v = smc[px][c];
                const float4* wr = reinterpret_cast<const float4*>(&fwS[c * 12]);
                float4 w0 = wr[0], w1 = wr[1];
                float w8 = fwS[c * 12 + 8];
                a[0] += v * w0.x; a[1] += v * w0.y; a[2] += v * w0.z; a[3] += v * w0.w;
                a[4] += v * w1.x; a[5] += v * w1.y; a[6] += v * w1.z; a[7] += v * w1.w;
                a[8] += v * w8;
            }
            float mx = a[0];
#pragma unroll
            for (int k = 1; k < 9; ++k) mx = fmaxf(mx, a[k]);
            float s = 0.f;
#pragma unroll
            for (int k = 0; k < 9; ++k) { a[k] = expf(a[k] - mx); s += a[k]; }
            float inv = 1.f / s;
#pragma unroll
            for (int k = 0; k < 9; ++k) kernS[px][k] = f2s(a[k] * inv);
        }
    } else if (q <= 4) {
        const int px = lane & 31;
        const int oc = ((q - 1) << 1) | (lane >> 5);
        float o = tb[oc], aa = tab[oc];
        for (int c = 0; c < 64; ++c) {
            float v = smc[px][c];
            o  += v * swS[(c << 4) + 2 * oc];
            aa += v * swS[(c << 4) + 2 * oc + 1];
        }
        int hw = ((ty * 4 + (px >> 3)) << 7) + tx * 8 + (px & 7);
        toff[((size_t)((b << 3) + oc) << 14) + hw] =
            o * (1.f / (1.f + expf(-aa)));
    }
    __syncthreads();

    // --- phase 4: 3x3 dynamic filter from LDS -> xfilt ---
    {
        const int chunk = threadIdx.x & 31;       // 8-channel chunk
        const int pxg = threadIdx.x >> 5;         // 0..15
#pragma unroll
        for (int it = 0; it < 2; ++it) {
            int p = (pxg << 1) + it;              // tile-linear px 0..31
            int ly = p >> 3, lx = p & 7;
            int gh = ty * 4 + ly, gw = tx * 8 + lx;
            float wk[9];
            short8 k8 = *(const short8*)&kernS[p][0];
#pragma unroll
            for (int k = 0; k < 8; ++k) wk[k] = s2f(k8[k]);
            wk[8] = s2f(kernS[p][8]);
            float ymask[3] = { gh > 0 ? 1.f : 0.f, 1.f, gh < 127 ? 1.f : 0.f };
            float xmask[3] = { gw > 0 ? 1.f : 0.f, 1.f, gw < 127 ? 1.f : 0.f };
            float sum[8];
#pragma unroll
            for (int jj = 0; jj < 8; ++jj) sum[jj] = 0.f;
#pragma unroll
            for (int dy = 0; dy < 3; ++dy) {
#pragma unroll
                for (int dx = 0; dx < 3; ++dx) {
                    float wgt = wk[dy * 3 + dx] * ymask[dy] * xmask[dx];
                    int r = (ly + dy) * 10 + lx + dx;
                    short8 v = *(const short8*)&xupS[(r << 8)
                                + (((chunk ^ (r & 7))) << 3)];
#pragma unroll
                    for (int jj = 0; jj < 8; ++jj) sum[jj] += wgt * s2f(v[jj]);
                }
            }
            short8 pk;
#pragma unroll
            for (int jj = 0; jj < 8; ++jj) pk[jj] = f2s(sum[jj]);
            int hw = (gh << 7) + gw;
            *(short8*)((short*)xfilt + ((size_t)((b << 14) + hw) << 8)
                       + chunk * 8) = pk;
        }
    }
}

// ---------------------------------------------------------------------------
// K6: trim_op -> out (b,256,16384) fp32. 1024 threads: 1 px-gather per lane.
// XCD-chunked swizzle -> per-XCD xfilt tap region ~4MB -> mostly L2-hit.
// ---------------------------------------------------------------------------
__global__ __launch_bounds__(1024, 4) void k6_trim(const bf16* __restrict__ xfilt,
        const float* __restrict__ toff, float* __restrict__ out)
{
    __shared__ __align__(16) float sm[32][258];
    const int nb = gridDim.x >> 3;
    const int vbid = (blockIdx.x & 7) * nb + (blockIdx.x >> 3);
    int b = vbid >> 9;
    int hw0 = (vbid & 511) << 5;
    int pp = threadIdx.x >> 5;      // px 0..31
    int cl = threadIdx.x & 31;      // 8-ch chunk
    int e = cl << 3;                // shorts / floats
    int g = cl >> 3;                // trim group (64 ch each)
    const short* xb = (const short*)xfilt + ((size_t)(b * HWD) << 8);
    const float* tfx = toff + ((size_t)(b * 8 + 2 * g)     << 14);
    const float* tfy = toff + ((size_t)(b * 8 + 2 * g + 1) << 14);

    {
        int hw = hw0 + pp;
        int h = hw >> 7, w = hw & 127;
        float ox = tfx[hw], oy = tfy[hw];
        float ix = fminf(fmaxf(w + ox, 0.f), 127.f);
        float iy = fminf(fmaxf(h + oy, 0.f), 127.f);
        float x0f = floorf(ix), y0f = floorf(iy);
        float fx = ix - x0f, fy = iy - y0f;
        int x0 = (int)x0f, y0 = (int)y0f;
        int x1 = min(x0 + 1, 127), y1 = min(y0 + 1, 127);
        float w00 = (1.f - fx) * (1.f - fy), w01 = fx * (1.f - fy);
        float w10 = (1.f - fx) * fy,        w11 = fx * fy;
        short8 v00 = *(const short8*)(xb + (((size_t)(y0 << 7) + x0) << 8) + e);
        short8 v01 = *(const short8*)(xb + (((size_t)(y0 << 7) + x1) << 8) + e);
        short8 v10 = *(const short8*)(xb + (((size_t)(y1 << 7) + x0) << 8) + e);
        short8 v11 = *(const short8*)(xb + (((size_t)(y1 << 7) + x1) << 8) + e);
#pragma unroll
        for (int jp = 0; jp < 4; ++jp) {
            float2 t;
            t.x = w00 * s2f(v00[2*jp])   + w01 * s2f(v01[2*jp])
                + w10 * s2f(v10[2*jp])   + w11 * s2f(v11[2*jp]);
            t.y = w00 * s2f(v00[2*jp+1]) + w01 * s2f(v01[2*jp+1])
                + w10 * s2f(v10[2*jp+1]) + w11 * s2f(v11[2*jp+1]);
            *(float2*)&sm[pp][e + 2*jp] = t;
        }
    }
    __syncthreads();
    int lp = threadIdx.x & 31;
    int cg = threadIdx.x >> 5;          // 0..31, 8 channels each
    float* ob = out + ((size_t)b << 22) + hw0 + lp;
#pragma unroll
    for (int k = 0; k < 8; ++k) {
        int c = (cg << 3) + k;
        ob[(size_t)c << 14] = sm[lp][c];
    }
}

extern "C" void kernel_launch(void* const* d_in, const int* in_sizes, int n_in,
                              void* d_out, int out_size, void* d_ws, size_t ws_size,
                              hipStream_t stream)
{
    const float* x       = (const float*)d_in[0];
    const float* w_off   = (const float*)d_in[1];
    const float* b_off   = (const float*)d_in[2];
    const float* w_ast   = (const float*)d_in[3];
    const float* b_ast   = (const float*)d_in[4];
    const float* comp_w  = (const float*)d_in[5];
    const float* comp_b  = (const float*)d_in[6];
    const float* filt_w  = (const float*)d_in[7];
    const float* filt_b  = (const float*)d_in[8];
    const float* trim_w  = (const float*)d_in[9];
    const float* trim_b  = (const float*)d_in[10];
    const float* trim_aw = (const float*)d_in[11];
    const float* trim_ab = (const float*)d_in[12];
    float* out = (float*)d_out;

    char* ws = (char*)d_ws;
    float* offpm = (float*)(ws);                 // 2 MiB (b,4096,32)
    bf16*  xpm   = (bf16*) (ws + (2ull << 20));  // 8 MiB pixel-major (b,4096,256)
    bf16*  xfilt = (bf16*) (ws + (16ull << 20)); // 32 MiB pixel-major (b,hw,256)
    float* toff  = (float*)(ws + (48ull << 20)); // 2 MiB (b,8,16384)

    hipLaunchKernelGGL(k01_xpose_off, dim3(512),  dim3(512), 0, stream,
                       x, w_off, b_off, w_ast, b_ast, xpm, offpm);
    hipLaunchKernelGGL(k234_defsample_comp_filter, dim3(2048), dim3(512), 0, stream,
                       xpm, offpm, comp_w, comp_b, filt_w, filt_b,
                       trim_w, trim_b, trim_aw, trim_ab, xfilt, toff);
    hipLaunchKernelGGL(k6_trim,     dim3(2048),  dim3(1024), 0, stream,
                       xfilt, toff, out);
}

// Round 9
// 163.398 us; speedup vs baseline: 1.1214x; 1.1214x over previous
//
#include <hip/hip_runtime.h>
#include <hip/hip_bf16.h>
#include <string.h>

typedef __hip_bfloat16 bf16;
typedef __attribute__((ext_vector_type(8))) short short8;
typedef __attribute__((ext_vector_type(4))) short short4v;
typedef __attribute__((ext_vector_type(4))) float f32x4;

__device__ __forceinline__ float s2f(short s) {
    return __uint_as_float(((unsigned)(unsigned short)s) << 16);
}
__device__ __forceinline__ short f2s(float v) {
    bf16 t = __float2bfloat16(v); short s; __builtin_memcpy(&s, &t, 2); return s;
}

#define HWD 16384    // 128*128

// ---------------------------------------------------------------------------
// K01 (R2-era best): transpose x -> xpm bf16 + off/ast MFMA from LDS.
// grid 256 = 4 b * 64 tiles(64 px); 512 threads (8 waves: 2 mh x 4 wq).
// ---------------------------------------------------------------------------
__global__ __launch_bounds__(512) void k01_xpose_off(const float* __restrict__ x,
        const float* __restrict__ w_off, const float* __restrict__ b_off,
        const float* __restrict__ w_ast, const float* __restrict__ b_ast,
        bf16* __restrict__ xpm, float* __restrict__ offpm)
{
    __shared__ __align__(16) short tileS[64 * 256];   // 32 KB, swizzled
    const int b = blockIdx.x >> 6;
    const int p0 = (blockIdx.x & 63) << 6;
    const int lane = threadIdx.x & 63;
    const int wave = threadIdx.x >> 6;      // 0..7
    const int n = lane & 15, quad = lane >> 4;
    const int wq = wave & 3;                // N-group
    const int mh = wave >> 2;               // m-half

    const int j = (wq << 4) + n, oc = j >> 1, kind = j & 1;
    short8 bfrag[8];
    const float* wrow = (kind ? w_ast : w_off) + oc * 256 + quad * 8;
#pragma unroll
    for (int kc = 0; kc < 8; ++kc) {
        float4 lo = *(const float4*)(wrow + kc * 32);
        float4 hi = *(const float4*)(wrow + kc * 32 + 4);
        short8 f;
        f[0] = f2s(lo.x); f[1] = f2s(lo.y); f[2] = f2s(lo.z); f[3] = f2s(lo.w);
        f[4] = f2s(hi.x); f[5] = f2s(hi.y); f[6] = f2s(hi.z); f[7] = f2s(hi.w);
        bfrag[kc] = f;
    }
    float bias = kind ? b_ast[oc] : b_off[oc];

    // --- phase 1: fill swizzled LDS tile ---
    {
        const float* xb = x + ((size_t)b << 20);
        const int lp = lane;
#pragma unroll
        for (int gg = 0; gg < 4; ++gg) {
            int cbase = (wave << 5) + (gg << 3);
            short8 pk;
#pragma unroll
            for (int jj = 0; jj < 8; ++jj)
                pk[jj] = f2s(xb[((size_t)(cbase + jj) << 12) + p0 + lp]);
            int slot = (cbase >> 3) ^ (lp & 7);
            *(short8*)&tileS[(lp << 8) + (slot << 3)] = pk;
        }
    }
    __syncthreads();

    // --- phase 2: coalesced xpm store from LDS ---
    {
        short* ob = (short*)xpm + ((size_t)((b << 12) + p0) << 8);
#pragma unroll
        for (int rr = 0; rr < 8; ++rr) {
            int r = (wave << 3) + rr;
            short4v v = *(const short4v*)&tileS[(r << 8)
                        + ((((lane >> 1) ^ (r & 7)) << 3) | ((lane & 1) << 2))];
            *(short4v*)(ob + ((size_t)r << 8) + (lane << 2)) = v;
        }
    }

    // --- phase 3: MFMA GEMM from LDS, gated epilogue -> offpm ---
    float* obase = offpm + ((size_t)(b << 12) << 5);
    f32x4 acc0 = {0.f, 0.f, 0.f, 0.f};
    f32x4 acc1 = {0.f, 0.f, 0.f, 0.f};
#pragma unroll
    for (int kc = 0; kc < 8; ++kc) {
        int slot = (((kc << 2) + quad) ^ (n & 7)) << 3;
        short8 a0 = *(const short8*)&tileS[((mh * 32 + n) << 8) + slot];
        short8 a1 = *(const short8*)&tileS[((mh * 32 + 16 + n) << 8) + slot];
        acc0 = __builtin_amdgcn_mfma_f32_16x16x32_bf16(a0, bfrag[kc], acc0, 0, 0, 0);
        acc1 = __builtin_amdgcn_mfma_f32_16x16x32_bf16(a1, bfrag[kc], acc1, 0, 0, 0);
    }
#pragma unroll
    for (int r = 0; r < 4; ++r) {
        float v0 = acc0[r] + bias;
        float v1 = acc1[r] + bias;
        float p0v = __shfl_xor(v0, 1, 64);
        float p1v = __shfl_xor(v1, 1, 64);
        if (!(n & 1)) {
            int px = p0 + mh * 32 + quad * 4 + r;
            obase[((size_t)px << 5) + oc] = v0 * (1.f / (1.f + expf(-p0v)));
            obase[((size_t)(px + 16) << 5) + oc] = v1 * (1.f / (1.f + expf(-p1v)));
        }
    }
}

// ---------------------------------------------------------------------------
// K234 (R7 best, 50.4 us measured): def_sample(10x10 halo) + comp MFMA +
// kern/toff epilogue + 3x3 filter. 8x8 tile, 78KB LDS, 4-deep pipelined
// gather, XCD-chunked swizzle. grid 1024; 512 threads.
// ---------------------------------------------------------------------------
__global__ __launch_bounds__(512, 4) void k234_defsample_comp_filter(
        const bf16* __restrict__ xpm, const float* __restrict__ offpm,
        const float* __restrict__ cw, const float* __restrict__ cb,
        const float* __restrict__ fw_g, const float* __restrict__ fb,
        const float* __restrict__ tw, const float* __restrict__ tb,
        const float* __restrict__ taw, const float* __restrict__ tab,
        bf16* __restrict__ xfilt, float* __restrict__ toff)
{
    __shared__ __align__(16) short xupS[100 * 256];   // 50 KB, swizzled rows
    __shared__ __align__(16) float smc[64][65];       // comp redistribution
    __shared__ __align__(16) float fwS[64 * 12];
    __shared__ __align__(16) float swS[64 * 16];
    __shared__ __align__(16) short kernS[64][24];     // 16B-aligned rows

    for (int i = threadIdx.x; i < 64 * 12; i += 512) {
        int c = i / 12, k = i % 12;
        fwS[i] = (k < 9) ? fw_g[k * 64 + c] : 0.f;
    }
    for (int i = threadIdx.x; i < 64 * 16; i += 512) {
        int c = i >> 4, jj = i & 15;
        int oc = jj >> 1, kind = jj & 1;
        swS[i] = kind ? taw[oc * 64 + c] : tw[oc * 64 + c];
    }

    // XCD-chunked bijective swizzle (grid 1024, 1024%8==0)
    const int nb = gridDim.x >> 3;
    const int vbid = (blockIdx.x & 7) * nb + (blockIdx.x >> 3);
    const int b = vbid >> 8;
    const int tile = vbid & 255;
    const int ty = tile >> 4, tx = tile & 15;
    const int lane = threadIdx.x & 63;
    const int wave = threadIdx.x >> 6;       // 0..7
    const int n = lane & 15, quad = lane >> 4;
    const int wq = wave & 3, mh = wave >> 2;
    const int ocb = wq << 4;

    // --- phase 1: gather halo pixels; 4-deep software-pipelined tap loads ---
    {
        const short* xsrc = (const short*)xpm + ((size_t)b << 20);
        const int ph = lane >> 5;             // px half
        const int cl = lane & 31;             // 8-ch chunk
        const int e = cl << 3;                // shorts
        const int g = cl >> 3;                // offset group
        const int base = (wave << 1) + ph;    // 0..15

        float2 fo[7];
#pragma unroll
        for (int it = 0; it < 7; ++it) {
            int l = base + (it << 4);
            if (l < 100) {
                int lhy = (l * 205) >> 11;    // l / 10
                int lwx = l - lhy * 10;
                int hy = min(max(ty * 8 - 1 + lhy, 0), 127);
                int wx = min(max(tx * 8 - 1 + lwx, 0), 127);
                int och = (g << 3) + ((hy & 1) << 2) + ((wx & 1) << 1);
                fo[it] = *(const float2*)(offpm
                        + ((size_t)((b << 12) + ((hy >> 1) << 6) + (wx >> 1)) << 5)
                        + och);
            }
        }

        short8 t00[4], t01[4], t10[4], t11[4];

#define K234_ISSUE(it, slot) { \
            int l = base + ((it) << 4); \
            if (l < 100) { \
                int lhy = (l * 205) >> 11; \
                int lwx = l - lhy * 10; \
                int hy = min(max(ty * 8 - 1 + lhy, 0), 127); \
                int wx = min(max(tx * 8 - 1 + lwx, 0), 127); \
                float ix = (wx + 0.5f + fo[it].x) * 0.5f - 0.5f; \
                float iy = (hy + 0.5f + fo[it].y) * 0.5f - 0.5f; \
                ix = fminf(fmaxf(ix, 0.f), 63.f); \
                iy = fminf(fmaxf(iy, 0.f), 63.f); \
                int x0 = (int)ix, y0 = (int)iy; \
                int x1 = min(x0 + 1, 63), y1 = min(y0 + 1, 63); \
                t00[slot] = *(const short8*)(xsrc + (((size_t)(y0 << 6) + x0) << 8) + e); \
                t01[slot] = *(const short8*)(xsrc + (((size_t)(y0 << 6) + x1) << 8) + e); \
                t10[slot] = *(const short8*)(xsrc + (((size_t)(y1 << 6) + x0) << 8) + e); \
                t11[slot] = *(const short8*)(xsrc + (((size_t)(y1 << 6) + x1) << 8) + e); \
            } }

#define K234_CONSUME(it, slot) { \
            int l = base + ((it) << 4); \
            if (l < 100) { \
                int lhy = (l * 205) >> 11; \
                int lwx = l - lhy * 10; \
                int hy = min(max(ty * 8 - 1 + lhy, 0), 127); \
                int wx = min(max(tx * 8 - 1 + lwx, 0), 127); \
                float ix = (wx + 0.5f + fo[it].x) * 0.5f - 0.5f; \
                float iy = (hy + 0.5f + fo[it].y) * 0.5f - 0.5f; \
                ix = fminf(fmaxf(ix, 0.f), 63.f); \
                iy = fminf(fmaxf(iy, 0.f), 63.f); \
                float fx = ix - floorf(ix), fy = iy - floorf(iy); \
                float w00 = (1.f - fx) * (1.f - fy), w01 = fx * (1.f - fy); \
                float w10 = (1.f - fx) * fy,        w11 = fx * fy; \
                short8 pk; \
                _Pragma("unroll") \
                for (int jj = 0; jj < 8; ++jj) { \
                    float v = w00 * s2f(t00[slot][jj]) + w01 * s2f(t01[slot][jj]) \
                            + w10 * s2f(t10[slot][jj]) + w11 * s2f(t11[slot][jj]); \
                    pk[jj] = f2s(v); \
                } \
                int sl2 = cl ^ (l & 7); \
                *(short8*)&xupS[(l << 8) + (sl2 << 3)] = pk; \
            } }

        K234_ISSUE(0, 0)
        K234_ISSUE(1, 1)
        K234_ISSUE(2, 2)
        K234_ISSUE(3, 3)
        K234_CONSUME(0, 0)  K234_ISSUE(4, 0)
        K234_CONSUME(1, 1)  K234_ISSUE(5, 1)
        K234_CONSUME(2, 2)  K234_ISSUE(6, 2)
        K234_CONSUME(3, 3)
        K234_CONSUME(4, 0)
        K234_CONSUME(5, 1)
        K234_CONSUME(6, 2)
#undef K234_ISSUE
#undef K234_CONSUME
    }

    // --- B fragments for comp GEMM (loaded after gather: VGPR headroom) ---
    short8 bfrag[8];
    {
        const float* wrow = cw + (ocb + n) * 256 + quad * 8;
#pragma unroll
        for (int kc = 0; kc < 8; ++kc) {
            float4 lo = *(const float4*)(wrow + kc * 32);
            float4 hi = *(const float4*)(wrow + kc * 32 + 4);
            short8 f;
            f[0] = f2s(lo.x); f[1] = f2s(lo.y); f[2] = f2s(lo.z); f[3] = f2s(lo.w);
            f[4] = f2s(hi.x); f[5] = f2s(hi.y); f[6] = f2s(hi.z); f[7] = f2s(hi.w);
            bfrag[kc] = f;
        }
    }
    float bias = cb[ocb + n];
    __syncthreads();

    // --- phase 2: comp MFMA; wave (mh,wq) does m-half mh, cols wq*16 ---
    const int m0 = mh << 5;
    const int pA = m0 + n, pB = m0 + 16 + n;
    const int rA = ((pA >> 3) + 1) * 10 + (pA & 7) + 1;
    const int rB = ((pB >> 3) + 1) * 10 + (pB & 7) + 1;
    f32x4 acc0 = {0.f,0.f,0.f,0.f}, acc1 = {0.f,0.f,0.f,0.f};
#pragma unroll
    for (int kc = 0; kc < 8; ++kc) {
        int sp = (kc << 2) + quad;
        short8 a0 = *(const short8*)&xupS[(rA << 8) + ((sp ^ (rA & 7)) << 3)];
        short8 a1 = *(const short8*)&xupS[(rB << 8) + ((sp ^ (rB & 7)) << 3)];
        acc0 = __builtin_amdgcn_mfma_f32_16x16x32_bf16(a0, bfrag[kc], acc0, 0, 0, 0);
        acc1 = __builtin_amdgcn_mfma_f32_16x16x32_bf16(a1, bfrag[kc], acc1, 0, 0, 0);
    }
#pragma unroll
    for (int r = 0; r < 4; ++r) {
        smc[m0 +      quad * 4 + r][ocb + n] = acc0[r] + bias;
        smc[m0 + 16 + quad * 4 + r][ocb + n] = acc1[r] + bias;
    }
    __syncthreads();

    // --- phase 3: kern softmax (wave 0) / toff (waves 1..4) ---
    const int px = lane;
    const int q = wave;
    if (q == 0) {
        float a[9];
#pragma unroll
        for (int k = 0; k < 9; ++k) a[k] = fb[k];
        for (int c = 0; c < 64; ++c) {
            float v = smc[px][c];
            const float4* wr = reinterpret_cast<const float4*>(&fwS[c * 12]);
            float4 w0 = wr[0], w1 = wr[1];
            float w8 = fwS[c * 12 + 8];
            a[0] += v * w0.x; a[1] += v * w0.y; a[2] += v * w0.z; a[3] += v * w0.w;
            a[4] += v * w1.x; a[5] += v * w1.y; a[6] += v * w1.z; a[7] += v * w1.w;
            a[8] += v * w8;
        }
        float mx = a[0];
#pragma unroll
        for (int k = 1; k < 9; ++k) mx = fmaxf(mx, a[k]);
        float s = 0.f;
#pragma unroll
        for (int k = 0; k < 9; ++k) { a[k] = expf(a[k] - mx); s += a[k]; }
        float inv = 1.f / s;
#pragma unroll
        for (int k = 0; k < 9; ++k) kernS[px][k] = f2s(a[k] * inv);
    } else if (q <= 4) {
        const int oc0 = (q - 1) << 1;
        float o[2], aa[2];
#pragma unroll
        for (int i = 0; i < 2; ++i) { o[i] = tb[oc0 + i]; aa[i] = tab[oc0 + i]; }
        for (int c = 0; c < 64; ++c) {
            float v = smc[px][c];
            const float* wr = &swS[c << 4];
#pragma unroll
            for (int i = 0; i < 2; ++i) {
                o[i]  += v * wr[2 * (oc0 + i)];
                aa[i] += v * wr[2 * (oc0 + i) + 1];
            }
        }
        int hw = ((ty * 8 + (px >> 3)) << 7) + tx * 8 + (px & 7);
#pragma unroll
        for (int i = 0; i < 2; ++i)
            toff[((size_t)((b << 3) + oc0 + i) << 14) + hw] =
                o[i] * (1.f / (1.f + expf(-aa[i])));
    }
    __syncthreads();

    // --- phase 4: 3x3 dynamic filter from LDS -> xfilt ---
    {
        const int chunk = threadIdx.x & 31;       // 8-channel chunk
        const int pxg = threadIdx.x >> 5;         // 0..15
#pragma unroll
        for (int it = 0; it < 4; ++it) {
            int p = (pxg << 2) + it;              // tile-linear px
            int ly = p >> 3, lx = p & 7;
            int gh = ty * 8 + ly, gw = tx * 8 + lx;
            float wk[9];
            short8 k8 = *(const short8*)&kernS[p][0];
#pragma unroll
            for (int k = 0; k < 8; ++k) wk[k] = s2f(k8[k]);
            wk[8] = s2f(kernS[p][8]);
            float ymask[3] = { gh > 0 ? 1.f : 0.f, 1.f, gh < 127 ? 1.f : 0.f };
            float xmask[3] = { gw > 0 ? 1.f : 0.f, 1.f, gw < 127 ? 1.f : 0.f };
            float sum[8];
#pragma unroll
            for (int jj = 0; jj < 8; ++jj) sum[jj] = 0.f;
#pragma unroll
            for (int dy = 0; dy < 3; ++dy) {
#pragma unroll
                for (int dx = 0; dx < 3; ++dx) {
                    float wgt = wk[dy * 3 + dx] * ymask[dy] * xmask[dx];
                    int r = (ly + dy) * 10 + lx + dx;
                    short8 v = *(const short8*)&xupS[(r << 8)
                                + (((chunk ^ (r & 7))) << 3)];
#pragma unroll
                    for (int jj = 0; jj < 8; ++jj) sum[jj] += wgt * s2f(v[jj]);
                }
            }
            short8 pk;
#pragma unroll
            for (int jj = 0; jj < 8; ++jj) pk[jj] = f2s(sum[jj]);
            int hw = (gh << 7) + gw;
            *(short8*)((short*)xfilt + ((size_t)((b << 14) + hw) << 8)
                       + chunk * 8) = pk;
        }
    }
}

// ---------------------------------------------------------------------------
// K6 (original best): trim_op -> out (b,256,16384) fp32.
// 256 threads; wave-per-8px gather into LDS; transposed coalesced stores.
// ---------------------------------------------------------------------------
__global__ __launch_bounds__(256) void k6_trim(const bf16* __restrict__ xfilt,
        const float* __restrict__ toff, float* __restrict__ out)
{
    __shared__ float sm[32][260];
    int b = blockIdx.x >> 9;
    int hw0 = (blockIdx.x & 511) << 5;
    int wave = threadIdx.x >> 6, lane = threadIdx.x & 63;
    int e = lane * 4;
    int g = lane >> 4;
    const short* xb = (const short*)xfilt + ((size_t)(b * HWD) << 8);
    const float* tfx = toff + ((size_t)(b * 8 + 2 * g)     << 14);
    const float* tfy = toff + ((size_t)(b * 8 + 2 * g + 1) << 14);

    for (int i = 0; i < 8; ++i) {
        int pp = wave * 8 + i;
        int hw = hw0 + pp;
        int h = hw >> 7, w = hw & 127;
        float ox = tfx[hw], oy = tfy[hw];
        float ix = fminf(fmaxf(w + ox, 0.f), 127.f);
        float iy = fminf(fmaxf(h + oy, 0.f), 127.f);
        float x0f = floorf(ix), y0f = floorf(iy);
        float fx = ix - x0f, fy = iy - y0f;
        int x0 = (int)x0f, y0 = (int)y0f;
        int x1 = min(x0 + 1, 127), y1 = min(y0 + 1, 127);
        float w00 = (1.f - fx) * (1.f - fy), w01 = fx * (1.f - fy);
        float w10 = (1.f - fx) * fy,        w11 = fx * fy;
        short4v v00 = *(const short4v*)(xb + (((size_t)(y0 << 7) + x0) << 8) + e);
        short4v v01 = *(const short4v*)(xb + (((size_t)(y0 << 7) + x1) << 8) + e);
        short4v v10 = *(const short4v*)(xb + (((size_t)(y1 << 7) + x0) << 8) + e);
        short4v v11 = *(const short4v*)(xb + (((size_t)(y1 << 7) + x1) << 8) + e);
#pragma unroll
        for (int j = 0; j < 4; ++j) {
            sm[pp][e + j] = w00 * s2f(v00[j]) + w01 * s2f(v01[j])
                          + w10 * s2f(v10[j]) + w11 * s2f(v11[j]);
        }
    }
    __syncthreads();
    int lp = threadIdx.x & 31;
    int c0 = (threadIdx.x >> 5) << 5;
    float* ob = out + (((size_t)b << 8) << 14) + hw0 + lp;
#pragma unroll 8
    for (int k = 0; k < 32; ++k) {
        int c = c0 + k;
        ob[(size_t)c << 14] = sm[lp][c];
    }
}

extern "C" void kernel_launch(void* const* d_in, const int* in_sizes, int n_in,
                              void* d_out, int out_size, void* d_ws, size_t ws_size,
                              hipStream_t stream)
{
    const float* x       = (const float*)d_in[0];
    const float* w_off   = (const float*)d_in[1];
    const float* b_off   = (const float*)d_in[2];
    const float* w_ast   = (const float*)d_in[3];
    const float* b_ast   = (const float*)d_in[4];
    const float* comp_w  = (const float*)d_in[5];
    const float* comp_b  = (const float*)d_in[6];
    const float* filt_w  = (const float*)d_in[7];
    const float* filt_b  = (const float*)d_in[8];
    const float* trim_w  = (const float*)d_in[9];
    const float* trim_b  = (const float*)d_in[10];
    const float* trim_aw = (const float*)d_in[11];
    const float* trim_ab = (const float*)d_in[12];
    float* out = (float*)d_out;

    char* ws = (char*)d_ws;
    float* offpm = (float*)(ws);                 // 2 MiB (b,4096,32)
    bf16*  xpm   = (bf16*) (ws + (2ull << 20));  // 8 MiB pixel-major (b,4096,256)
    bf16*  xfilt = (bf16*) (ws + (16ull << 20)); // 32 MiB pixel-major (b,hw,256)
    float* toff  = (float*)(ws + (48ull << 20)); // 2 MiB (b,8,16384)

    hipLaunchKernelGGL(k01_xpose_off, dim3(256),  dim3(512), 0, stream,
                       x, w_off, b_off, w_ast, b_ast, xpm, offpm);
    hipLaunchKernelGGL(k234_defsample_comp_filter, dim3(1024), dim3(512), 0, stream,
                       xpm, offpm, comp_w, comp_b, filt_w, filt_b,
                       trim_w, trim_b, trim_aw, trim_ab, xfilt, toff);
    hipLaunchKernelGGL(k6_trim,     dim3(2048),  dim3(256), 0, stream,
                       xfilt, toff, out);
}